// Round 9
// baseline (3121.893 us; speedup 1.0000x reference)
//
#include <hip/hip_runtime.h>
#include <hip/hip_bf16.h>

typedef unsigned short u16;

#define PTS_STRIDE (387*4096)

// ---- scratch layout (bytes), all fp32, no aliasing ----
#define OFF_CVF  0ll
#define OFF_NF   19774464ll
#define OFF_QKV  32357376ll
#define OFF_AOP  70106112ll
#define OFF_CAT1 82689024ll
#define OFF_A1   107854848ll
#define OFF_A2   120437760ll
#define OFF_OUT1 133020672ll
#define OFF_OUT2 145603584ll
#define OFF_H1   158186496ll
#define OFF_FIN  183352320ll
#define OFF_IDX  195935232ll
#define OFF_S    196197376ll
#define OFF_P    1001503744ll
#define WS_NEED  1806810112ull

// converted-input element offsets (float elements) within CVF
#define CV_POINTS     0ll
#define CV_LN1G 3170304ll
#define CV_LN1B 3170688ll
#define CV_QKVW 3171072ll
#define CV_AOW  3613440ll
#define CV_AOB  3760896ll
#define CV_KNNW 3761280ll
#define CV_KNNB 4056192ll
#define CV_MRGW 4056576ll
#define CV_MRGB 4351488ll
#define CV_LN2G 4351872ll
#define CV_LN2B 4352256ll
#define CV_FF1W 4352640ll
#define CV_FF1B 4647552ll
#define CV_FF2W 4648320ll
#define CV_FF2B 4943232ll

static char* g_scratch = nullptr;
__attribute__((constructor)) static void athena_ws_init(void){
  void* p = nullptr;
  if (hipMalloc(&p, WS_NEED) != hipSuccess) p = nullptr;
  g_scratch = (char*)p;
}

static __device__ __forceinline__ float bf2f(u16 u){
  union { unsigned int i; float f; } x; x.i = ((unsigned int)u) << 16; return x.f;
}

// ---------------- input conversion -> fp32 (probe ln1_g for dtype) ----------------
struct InPtrs { const void* p[16]; };
__global__ __launch_bounds__(256) void convert_inputs(float* dst, InPtrs ip)
{
  // ln1_g[0] == 1.0: bf16 -> first u16 = 0x3F80; fp32 -> first u16 = 0x0000.
  const bool isbf = (((const u16*)ip.p[1])[0] == 0x3F80);
  const int sizes[16] = {3170304, 384, 384, 442368, 147456, 384, 294912, 384,
                         294912, 384, 384, 384, 294912, 768, 294912, 384};
  const int tid = blockIdx.x*256 + threadIdx.x;
  const int nth = gridDim.x*256;
  long base = 0;
  for (int s = 0; s < 16; ++s){
    const int n = sizes[s];
    if (isbf){
      const u16* sp = (const u16*)ip.p[s];
      for (int i = tid; i < n; i += nth) dst[base+i] = bf2f(sp[i]);
    } else {
      const float* sp = (const float*)ip.p[s];
      for (int i = tid; i < n; i += nth) dst[base+i] = sp[i];
    }
    base += n;
  }
}

// ---------------- LayerNorm fp32 ----------------
__global__ __launch_bounds__(256) void ln_kernel(
    const float* __restrict__ in, const float* __restrict__ g,
    const float* __restrict__ bb, float* __restrict__ out, int mode)
{
  const int w = threadIdx.x >> 6, lane = threadIdx.x & 63;
  const int row = blockIdx.x * 4 + w;      // b*4096+n
  const int b = row >> 12, n = row & 4095;
  float x[6];
#pragma unroll
  for (int i = 0; i < 6; ++i){
    int d = lane + i*64;
    long off = (mode == 0) ? ((long)b*PTS_STRIDE + (long)(3+d)*4096 + n)
                           : ((long)row*384 + d);
    x[i] = in[off];
  }
  float s = 0.f;
#pragma unroll
  for (int i = 0; i < 6; ++i) s += x[i];
#pragma unroll
  for (int off = 1; off < 64; off <<= 1) s += __shfl_xor(s, off);
  float mean = s * (1.f/384.f);
  float vs = 0.f;
#pragma unroll
  for (int i = 0; i < 6; ++i){ float d = x[i]-mean; vs += d*d; }
#pragma unroll
  for (int off = 1; off < 64; off <<= 1) vs += __shfl_xor(vs, off);
  float rstd = 1.f / sqrtf(vs * (1.f/384.f) + 1e-5f);
#pragma unroll
  for (int i = 0; i < 6; ++i){
    int d = lane + i*64;
    out[(long)row*384 + d] = (x[i]-mean)*rstd*g[d] + bb[d];
  }
}

// ---------------- naive tiled SGEMM (fp32, VALU only) ----------
// C[M,N] = scale*(A@B) (+bias, +gelu, +resid). Batched over z=(zb*6+zh).
// bt=1: B stored [N][K] row-major (row stride ldb). M,N multiples of 64; K of 16.
__global__ __launch_bounds__(256) void sgemm_k(
    const float* __restrict__ A0, int lda, long asb, long ash,
    const float* __restrict__ B0, int ldb, long bsb, long bsh, int bt,
    float* __restrict__ C0, int ldc, long csb, long csh,
    const float* __restrict__ bias,
    const float* __restrict__ resid, int ldr,
    int Kd, int act, float scale)
{
  const int z = blockIdx.z, zb = z/6, zh = z - zb*6;
  const float* A = A0 + zb*asb + zh*ash;
  const float* B = B0 + zb*bsb + zh*bsh;
  float* C = C0 + zb*csb + zh*csh;

  const int n0 = blockIdx.x*64, m0 = blockIdx.y*64;
  const int tid = threadIdx.x, tx = tid & 15, ty = tid >> 4;

  __shared__ float As[64][17];   // [m][k]
  __shared__ float Bs[16][65];   // [k][n]

  float acc[4][4] = {};

  for (int k0 = 0; k0 < Kd; k0 += 16){
    __syncthreads();
#pragma unroll
    for (int l = 0; l < 4; ++l){           // A tile: 64x16
      int i = l*256 + tid, m = i >> 4, kk = i & 15;
      As[m][kk] = A[(long)(m0+m)*lda + k0 + kk];
    }
    if (bt){
#pragma unroll
      for (int l = 0; l < 4; ++l){         // B^T tile
        int i = l*256 + tid, n = i & 63, kk = i >> 6;
        Bs[kk][n] = B[(long)(n0+n)*ldb + k0 + kk];
      }
    } else {
#pragma unroll
      for (int l = 0; l < 4; ++l){         // B row-major tile
        int i = l*256 + tid, n = i & 63, kk = i >> 6;
        Bs[kk][n] = B[(long)(k0+kk)*ldb + n0 + n];
      }
    }
    __syncthreads();
#pragma unroll
    for (int kk = 0; kk < 16; ++kk){
      float a4[4], b4[4];
#pragma unroll
      for (int i = 0; i < 4; ++i) a4[i] = As[ty*4+i][kk];
#pragma unroll
      for (int j = 0; j < 4; ++j) b4[j] = Bs[kk][tx*4+j];
#pragma unroll
      for (int i = 0; i < 4; ++i)
#pragma unroll
        for (int j = 0; j < 4; ++j) acc[i][j] += a4[i]*b4[j];
    }
  }
#pragma unroll
  for (int i = 0; i < 4; ++i){
    int row = m0 + ty*4 + i;
#pragma unroll
    for (int j = 0; j < 4; ++j){
      int col = n0 + tx*4 + j;
      float v = acc[i][j]*scale + (bias ? bias[col] : 0.f);
      if (act == 1) v = 0.5f * v * (1.f + erff(v * 0.70710678f));
      if (resid) v += resid[(long)row*ldr + col];
      C[(long)row*ldc + col] = v;
    }
  }
}

// ---------------- exact row softmax fp32 ----------------
__global__ __launch_bounds__(256) void softmax_k(
    const float* __restrict__ S, float* __restrict__ P)
{
  const long row = (long)blockIdx.x*4 + (threadIdx.x>>6);
  const int lane = threadIdx.x & 63;
  const float* sr = S + row*4096;
  float* pr = P + row*4096;
  float m = -3.0e38f;
  for (int i = lane; i < 4096; i += 64) m = fmaxf(m, sr[i]);
#pragma unroll
  for (int off = 1; off < 64; off <<= 1) m = fmaxf(m, __shfl_xor(m, off));
  float s = 0.f;
  for (int i = lane; i < 4096; i += 64) s += expf(sr[i]-m);
#pragma unroll
  for (int off = 1; off < 64; off <<= 1) s += __shfl_xor(s, off);
  const float inv = 1.f / s;
  for (int i = lane; i < 4096; i += 64) pr[i] = expf(sr[i]-m)*inv;
}

// ---------------- KNN top-8 fp32 (IEEE ops, no fma contraction) ----------------
__global__ __launch_bounds__(256) void knn_topk(
    const float* __restrict__ pts, int* __restrict__ idxout)
{
  const int w = threadIdx.x >> 6, lane = threadIdx.x & 63;
  const int row = blockIdx.x * 4 + w;
  const int b = row >> 12, n = row & 4095;
  const long pb = (long)b * PTS_STRIDE;
  const float xn = pts[pb + n], yn = pts[pb + 4096 + n], zn = pts[pb + 8192 + n];
  const float sqn = __fadd_rn(__fadd_rn(__fmul_rn(xn,xn), __fmul_rn(yn,yn)), __fmul_rn(zn,zn));

  float bd[8]; int bi[8];
#pragma unroll
  for (int j = 0; j < 8; ++j){ bd[j] = 3.4e38f; bi[j] = 0x7fffffff; }

  for (int m0 = 0; m0 < 4096; m0 += 64){
    const int m = m0 + lane;
    float xm = pts[pb + m], ym = pts[pb + 4096 + m], zm = pts[pb + 8192 + m];
    float sqm = __fadd_rn(__fadd_rn(__fmul_rn(xm,xm), __fmul_rn(ym,ym)), __fmul_rn(zm,zm));
    float dot = __fadd_rn(__fadd_rn(__fmul_rn(xn,xm), __fmul_rn(yn,ym)), __fmul_rn(zn,zm));
    float v = __fadd_rn(__fadd_rn(sqn, sqm), __fmul_rn(-2.f, dot));
    int vi = m;
#pragma unroll
    for (int j = 0; j < 8; ++j){
      bool c = (v < bd[j]) || (v == bd[j] && vi < bi[j]);
      float td = bd[j]; int ti = bi[j];
      bd[j] = c ? v : td;  bi[j] = c ? vi : ti;
      v = c ? td : v;      vi = c ? ti : vi;
    }
  }
  for (int t = 0; t < 8; ++t){
    float rd = bd[0]; int ri = bi[0]; int rl = lane;
#pragma unroll
    for (int off = 1; off < 64; off <<= 1){
      float od = __shfl_xor(rd, off); int oi = __shfl_xor(ri, off); int ol = __shfl_xor(rl, off);
      bool take = (od < rd) || (od == rd && oi < ri);
      rd = take ? od : rd; ri = take ? oi : ri; rl = take ? ol : rl;
    }
    if (lane == 0) idxout[row*8 + t] = ri;
    if (lane == rl){
#pragma unroll
      for (int j = 0; j < 7; ++j){ bd[j] = bd[j+1]; bi[j] = bi[j+1]; }
      bd[7] = 3.4e38f; bi[7] = 0x7fffffff;
    }
  }
}

// ---------------- gather-max fp32 -> cat1 cols 384..767 ----------------
__global__ __launch_bounds__(384) void knn_gather_max(
    const float* __restrict__ A1, const float* __restrict__ A2,
    const int* __restrict__ idx, float* __restrict__ cat1)
{
  const int row = blockIdx.x;
  const int d = threadIdx.x;
  const int b = row >> 12;
  const float bs = A2[(long)row*384 + d] - A1[(long)row*384 + d];
  float mx = -3.4e38f;
#pragma unroll
  for (int k = 0; k < 8; ++k){
    int r = idx[row*8 + k] & 4095;
    float v = A1[(long)(b*4096 + r)*384 + d] + bs;
    v = (v > 0.f) ? v : 0.2f*v;
    mx = fmaxf(mx, v);
  }
  cat1[(long)row*768 + 384 + d] = mx;
}

// ---------------- coords passthrough: fp32 -> fp32 out ----------------
__global__ void copy_coords(const float* __restrict__ pts, float* __restrict__ out)
{
  int t = blockIdx.x*256 + threadIdx.x;     // 24576 total
  int b = t / 12288, r = t % 12288;
  long off = (long)b*PTS_STRIDE + r;
  out[off] = pts[off];
}

// ---------------- transpose fin fp32 (B,N,384) -> fp32 out channels 3..386 ----------
__global__ __launch_bounds__(256) void write_out(
    const float* __restrict__ fin, float* __restrict__ out)
{
  __shared__ float tile[64][65];
  const int n0 = blockIdx.x*64, d0 = blockIdx.y*64, b = blockIdx.z;
  const int t = threadIdx.x;
  {
    int nn = t >> 2, dc = (t & 3) * 16;
    const float* src = &fin[((long)(b*4096 + n0 + nn))*384 + d0 + dc];
#pragma unroll
    for (int j = 0; j < 16; ++j) tile[nn][dc + j] = src[j];
  }
  __syncthreads();
  {
    int dd = t >> 2, nc = (t & 3) * 16;
    float* dst = &out[(long)b*PTS_STRIDE + (long)(3+d0+dd)*4096 + n0 + nc];
#pragma unroll
    for (int j = 0; j < 16; ++j) dst[j] = tile[nc + j][dd];
  }
}

extern "C" void kernel_launch(void* const* d_in, const int* in_sizes, int n_in,
                              void* d_out, int out_size, void* d_ws, size_t ws_size,
                              hipStream_t stream) {
  (void)in_sizes; (void)n_in; (void)out_size; (void)ws_size; (void)d_ws;
  float* out = (float*)d_out;          // reference output dtype = float32
  char* ws = g_scratch;

  float* cvf  = (float*)(ws + OFF_CVF);
  float* nf   = (float*)(ws + OFF_NF);
  float* qkv  = (float*)(ws + OFF_QKV);
  float* aop  = (float*)(ws + OFF_AOP);
  float* cat1 = (float*)(ws + OFF_CAT1);
  float* A1b  = (float*)(ws + OFF_A1);
  float* A2b  = (float*)(ws + OFF_A2);
  float* out1 = (float*)(ws + OFF_OUT1);
  float* out2 = (float*)(ws + OFF_OUT2);
  float* h1   = (float*)(ws + OFF_H1);
  float* fin  = (float*)(ws + OFF_FIN);
  int*   idxb = (int*)(ws + OFF_IDX);
  float* Sb   = (float*)(ws + OFF_S);
  float* Pb   = (float*)(ws + OFF_P);

  const float *c_points = cvf+CV_POINTS, *c_ln1g = cvf+CV_LN1G, *c_ln1b = cvf+CV_LN1B,
              *c_qkvw = cvf+CV_QKVW, *c_aow = cvf+CV_AOW, *c_aob = cvf+CV_AOB,
              *c_knnw = cvf+CV_KNNW, *c_knnb = cvf+CV_KNNB, *c_mrgw = cvf+CV_MRGW,
              *c_mrgb = cvf+CV_MRGB, *c_ln2g = cvf+CV_LN2G, *c_ln2b = cvf+CV_LN2B,
              *c_ff1w = cvf+CV_FF1W, *c_ff1b = cvf+CV_FF1B, *c_ff2w = cvf+CV_FF2W,
              *c_ff2b = cvf+CV_FF2B;

  // 0. inputs -> fp32 (dtype probe inside)
  InPtrs ip; for (int i = 0; i < 16; ++i) ip.p[i] = d_in[i];
  convert_inputs<<<1024, 256, 0, stream>>>(cvf, ip);

  // 1. LN1 -> nf
  ln_kernel<<<2048, 256, 0, stream>>>(c_points, c_ln1g, c_ln1b, nf, 0);
  // 2. qkv = nf @ qkv_w (row-major weights, bt=0)
  sgemm_k<<<dim3(18,128,1), 256, 0, stream>>>(nf, 384, 0, 0,
      c_qkvw, 1152, 0, 0, 0, qkv, 1152, 0, 0, nullptr, nullptr, 0, 384, 0, 1.f);
  // 3a. S = (Q @ K^T)/8, batched over z=b*6+h
  sgemm_k<<<dim3(64,64,12), 256, 0, stream>>>(qkv, 1152, 4718592, 64,
      qkv+384, 1152, 4718592, 64, 1,
      Sb, 4096, 100663296, 16777216, nullptr, nullptr, 0, 64, 0, 0.125f);
  // 3b. P = softmax(S)
  softmax_k<<<12288, 256, 0, stream>>>(Sb, Pb);
  // 3c. O = P @ V -> aop (merged heads)
  sgemm_k<<<dim3(1,64,12), 256, 0, stream>>>(Pb, 4096, 100663296, 16777216,
      qkv+768, 1152, 4718592, 64, 0,
      aop, 384, 1572864, 64, nullptr, nullptr, 0, 4096, 0, 1.f);
  // 4. attn = aop @ attn_out_w + b -> cat1 cols 0..383
  sgemm_k<<<dim3(6,128,1), 256, 0, stream>>>(aop, 384, 0, 0,
      c_aow, 384, 0, 0, 0, cat1, 768, 0, 0, c_aob, nullptr, 0, 384, 0, 1.f);
  // 5. top-8 neighbors (fp32 coords)
  knn_topk<<<2048, 256, 0, stream>>>(c_points, idxb);
  // 6. A1 = nf@W1 ; A2 = nf@W2 + knn_b  (knn_w row halves)
  sgemm_k<<<dim3(6,128,1), 256, 0, stream>>>(nf, 384, 0, 0,
      c_knnw, 384, 0, 0, 0, A1b, 384, 0, 0, nullptr, nullptr, 0, 384, 0, 1.f);
  sgemm_k<<<dim3(6,128,1), 256, 0, stream>>>(nf, 384, 0, 0,
      c_knnw + 384*384, 384, 0, 0, 0, A2b, 384, 0, 0, c_knnb, nullptr, 0, 384, 0, 1.f);
  // 7. geom -> cat1 cols 384..767
  knn_gather_max<<<8192, 384, 0, stream>>>(A1b, A2b, idxb, cat1);
  // 8. out1 = cat1 @ merge_w + merge_b + attn(resid = cat1 cols 0..383)
  sgemm_k<<<dim3(6,128,1), 256, 0, stream>>>(cat1, 768, 0, 0,
      c_mrgw, 384, 0, 0, 0, out1, 384, 0, 0, c_mrgb, cat1, 768, 768, 0, 1.f);
  // 9. LN2
  ln_kernel<<<2048, 256, 0, stream>>>(out1, c_ln2g, c_ln2b, out2, 1);
  // 10. h1 = gelu(out2 @ ff1_w + ff1_b)
  sgemm_k<<<dim3(12,128,1), 256, 0, stream>>>(out2, 384, 0, 0,
      c_ff1w, 768, 0, 0, 0, h1, 768, 0, 0, c_ff1b, nullptr, 0, 384, 1, 1.f);
  // 11. fin = h1 @ ff2_w + ff2_b + out2
  sgemm_k<<<dim3(6,128,1), 256, 0, stream>>>(h1, 768, 0, 0,
      c_ff2w, 384, 0, 0, 0, fin, 384, 0, 0, c_ff2b, out2, 384, 768, 0, 1.f);
  // 12. assemble output (fp32)
  copy_coords<<<96, 256, 0, stream>>>(c_points, out);
  write_out<<<dim3(64,6,2), 256, 0, stream>>>(fin, out);
}

// Round 10
// 680.841 us; speedup vs baseline: 4.5854x; 4.5854x over previous
//
#include <hip/hip_runtime.h>
#include <hip/hip_bf16.h>

typedef unsigned short u16;
typedef __bf16 bf16x8 __attribute__((ext_vector_type(8)));
typedef float f32x4 __attribute__((ext_vector_type(4)));

#define PTS_STRIDE (387*4096)

// ---- scratch layout (bytes), no aliasing ----
#define OFF_CONV 0ll            // bf16 copies of all 16 inputs
#define OFF_CRDF 9887232ll      // fp32 compact coords [b][c][n] 2x3x4096
#define OFF_WT   9985536ll      // transposed weights bf16
#define OFF_NF   13524480ll
#define OFF_QKV  19815936ll
#define OFF_AOP  38690304ll
#define OFF_CAT1 44981760ll
#define OFF_A1   57564672ll
#define OFF_A2   63856128ll
#define OFF_OUT1 70147584ll
#define OFF_OUT2 76439040ll
#define OFF_H1   82730496ll
#define OFF_FIN  95313408ll     // fp32
#define OFF_IDX  107896320ll
#define WS_NEED  108158464ull

// converted-input element offsets within CONV (u16 elements)
#define CV_POINTS     0ll
#define CV_LN1G 3170304ll
#define CV_LN1B 3170688ll
#define CV_QKVW 3171072ll
#define CV_AOW  3613440ll
#define CV_AOB  3760896ll
#define CV_KNNW 3761280ll
#define CV_KNNB 4056192ll
#define CV_MRGW 4056576ll
#define CV_MRGB 4351488ll
#define CV_LN2G 4351872ll
#define CV_LN2B 4352256ll
#define CV_FF1W 4352640ll
#define CV_FF1B 4647552ll
#define CV_FF2W 4648320ll
#define CV_FF2B 4943232ll

// transposed-weight element offsets within WT (u16 elements)
#define WT_QKV 0ll
#define WT_AO  442368ll
#define WT_KNN 589824ll
#define WT_MRG 884736ll
#define WT_FF1 1179648ll
#define WT_FF2 1474560ll

static char* g_scratch = nullptr;
__attribute__((constructor)) static void athena_ws_init(void){
  void* p = nullptr;
  if (hipMalloc(&p, WS_NEED) != hipSuccess) p = nullptr;
  g_scratch = (char*)p;
}

static __device__ __forceinline__ float bf2f(u16 u){
  union { unsigned int i; float f; } x; x.i = ((unsigned int)u) << 16; return x.f;
}
static __device__ __forceinline__ u16 f2bf(float f){
  __hip_bfloat16 h = __float2bfloat16(f);
  u16 u; __builtin_memcpy(&u, &h, 2); return u;
}
static __device__ __forceinline__ float safe_exp(float x){
  return exp2f(fmaxf(x, -60.f) * 1.44269504f);
}

// ---------------- input conversion -> bf16 (+ fp32 compact coords) ----------------
struct InPtrs { const void* p[16]; };
__global__ __launch_bounds__(256) void convert_inputs(
    u16* dst, float* crd, InPtrs ip)
{
  // ln1_g[0]==1.0: bf16 -> first u16 = 0x3F80; fp32 -> 0x0000.
  const bool isbf = (((const u16*)ip.p[1])[0] == 0x3F80);
  const int sizes[16] = {3170304, 384, 384, 442368, 147456, 384, 294912, 384,
                         294912, 384, 384, 384, 294912, 768, 294912, 384};
  const int tid = blockIdx.x*256 + threadIdx.x;
  const int nth = gridDim.x*256;
  long base = 0;
  for (int s = 0; s < 16; ++s){
    const int n = sizes[s];
    if (isbf){
      const u16* sp = (const u16*)ip.p[s];
      for (int i = tid; i < n; i += nth) dst[base+i] = sp[i];
    } else {
      const float* sp = (const float*)ip.p[s];
      for (int i = tid; i < n; i += nth) dst[base+i] = f2bf(sp[i]);
    }
    base += n;
  }
  // compact fp32 coords: crd[b*12288 + c*4096 + n]
  for (int i = tid; i < 24576; i += nth){
    int b = i / 12288, r = i % 12288;
    long off = (long)b*PTS_STRIDE + r;
    crd[i] = isbf ? bf2f(((const u16*)ip.p[0])[off]) : ((const float*)ip.p[0])[off];
  }
}

// ---------------- transpose: in[R][C] -> out[C][R] (bf16) ----------------
__global__ __launch_bounds__(256) void transpose_k(
    const u16* __restrict__ in, u16* __restrict__ out, int R, int C)
{
  int total = R*C;
  for (int i = blockIdx.x*256 + threadIdx.x; i < total; i += gridDim.x*256){
    int r = i / C, c = i - r*C;
    out[(long)c*R + r] = in[i];
  }
}

// ---------------- LayerNorm bf16 (fp32 internal) ----------------
__global__ __launch_bounds__(256) void ln_kernel(
    const u16* __restrict__ in, const u16* __restrict__ g,
    const u16* __restrict__ bb, u16* __restrict__ out, int mode)
{
  const int w = threadIdx.x >> 6, lane = threadIdx.x & 63;
  const int row = blockIdx.x * 4 + w;
  const int b = row >> 12, n = row & 4095;
  float x[6];
#pragma unroll
  for (int i = 0; i < 6; ++i){
    int d = lane + i*64;
    long off = (mode == 0) ? ((long)b*PTS_STRIDE + (long)(3+d)*4096 + n)
                           : ((long)row*384 + d);
    x[i] = bf2f(in[off]);
  }
  float s = 0.f;
#pragma unroll
  for (int i = 0; i < 6; ++i) s += x[i];
#pragma unroll
  for (int off = 1; off < 64; off <<= 1) s += __shfl_xor(s, off);
  float mean = s * (1.f/384.f);
  float vs = 0.f;
#pragma unroll
  for (int i = 0; i < 6; ++i){ float d = x[i]-mean; vs += d*d; }
#pragma unroll
  for (int off = 1; off < 64; off <<= 1) vs += __shfl_xor(vs, off);
  float rstd = 1.f / sqrtf(vs * (1.f/384.f) + 1e-5f);
#pragma unroll
  for (int i = 0; i < 6; ++i){
    int d = lane + i*64;
    out[(long)row*384 + d] = f2bf((x[i]-mean)*rstd*bf2f(g[d]) + bf2f(bb[d]));
  }
}

// ---------------- Unified bf16 MFMA GEMM ----------------
// C[M,N] = A@B (+bias, +gelu, +resid). bt=1: B stored [N][K].
// cf32: write fp32. M,N mult of 64; K mult of 32.
__global__ __launch_bounds__(256) void gemm_k(
    const u16* __restrict__ A, int lda,
    const u16* __restrict__ B, int ldb, int bt,
    void* C0, int ldc, int cf32,
    const u16* __restrict__ bias,
    const u16* __restrict__ resid, int ldr,
    int Kd, int act)
{
  const int n0 = blockIdx.x*64, m0 = blockIdx.y*64;
  const int tid = threadIdx.x;
  const int w = tid>>6, lane = tid&63, quad = lane>>4, l16 = lane&15;

  __shared__ u16 As[64*40];
  __shared__ u16 Bs[64*40];

  f32x4 acc[4] = { {0,0,0,0},{0,0,0,0},{0,0,0,0},{0,0,0,0} };
  const int am = tid>>2, ak = (tid&3)*8;

  for (int k0 = 0; k0 < Kd; k0 += 32){
    __syncthreads();
    *(uint4*)&As[am*40+ak] = *(const uint4*)&A[(long)(m0+am)*lda + k0+ak];
    if (bt){
      *(uint4*)&Bs[am*40+ak] = *(const uint4*)&B[(long)(n0+am)*ldb + k0+ak];
    } else {
      const int bn = lane, bk = w*8;
      union { uint4 v; u16 s[8]; } tb;
#pragma unroll
      for (int j = 0; j < 8; ++j) tb.s[j] = B[(long)(k0+bk+j)*ldb + n0+bn];
      *(uint4*)&Bs[bn*40+bk] = tb.v;
    }
    __syncthreads();
    bf16x8 af = *(const bf16x8*)&As[(w*16+l16)*40 + quad*8];
#pragma unroll
    for (int nt = 0; nt < 4; ++nt){
      bf16x8 bfv = *(const bf16x8*)&Bs[(nt*16+l16)*40 + quad*8];
      acc[nt] = __builtin_amdgcn_mfma_f32_16x16x32_bf16(af, bfv, acc[nt], 0, 0, 0);
    }
  }
#pragma unroll
  for (int nt = 0; nt < 4; ++nt){
    int col = n0 + nt*16 + l16;
    float bv = bias ? bf2f(bias[col]) : 0.f;
#pragma unroll
    for (int r = 0; r < 4; ++r){
      int row = m0 + w*16 + quad*4 + r;     // C/D: row=quad*4+r, col=l16 (m89)
      float v = acc[nt][r] + bv;
      if (act == 1) v = 0.5f * v * (1.f + erff(v * 0.70710678f));
      if (resid) v += bf2f(resid[(long)row*ldr + col]);
      if (cf32) ((float*)C0)[(long)row*ldc + col] = v;
      else      ((u16*)C0)[(long)row*ldc + col] = f2bf(v);
    }
  }
}

// ---------------- Flash attention: qkv -> merged-head aop ----------------
// grid = (N/64, H, B), block = 256 (4 waves, 16 q-rows each). K-tile = 64.
__global__ __launch_bounds__(256) void flash_attn(
    const u16* __restrict__ qkv, u16* __restrict__ aop)
{
  __shared__ u16 vt[64*72];   // V^T tile [d][kk]
  __shared__ u16 pl[64*72];   // P tile [m][kk]
  const int tid = threadIdx.x;
  const int w = tid >> 6, lane = tid & 63;
  const int quad = lane >> 4, l16 = lane & 15;
  const int q0 = blockIdx.x * 64, h = blockIdx.y, b = blockIdx.z;
  const long base = (long)b * 4096 * 1152;

  bf16x8 qf[2];
  {
    const long qoff = base + (long)(q0 + w*16 + l16)*1152 + h*64;
#pragma unroll
    for (int ks = 0; ks < 2; ++ks)
      qf[ks] = *(const bf16x8*)&qkv[qoff + ks*32 + quad*8];
  }
  f32x4 o[4] = { {0,0,0,0},{0,0,0,0},{0,0,0,0},{0,0,0,0} };
  float mi[4], li[4];
#pragma unroll
  for (int r = 0; r < 4; ++r){ mi[r] = -1.0e30f; li[r] = 0.f; }

  const int vkk = tid & 63, vdb = (tid >> 6) * 16;

  for (int kt = 0; kt < 64; ++kt){
    { // stage V^T
      const u16* vr = &qkv[base + (long)(kt*64 + vkk)*1152 + 768 + h*64 + vdb];
      union { uint4 v[2]; u16 s[16]; } tv;
      tv.v[0] = *(const uint4*)vr;
      tv.v[1] = *(const uint4*)(vr + 8);
#pragma unroll
      for (int j = 0; j < 16; ++j) vt[(vdb+j)*72 + vkk] = tv.s[j];
    }
    __syncthreads();

    // S = (Q @ K^T)/8
    f32x4 s[4];
#pragma unroll
    for (int nt = 0; nt < 4; ++nt){
      f32x4 z = {0,0,0,0};
#pragma unroll
      for (int ks = 0; ks < 2; ++ks){
        bf16x8 kf = *(const bf16x8*)&qkv[base + (long)(kt*64 + nt*16 + l16)*1152 + 384 + h*64 + ks*32 + quad*8];
        z = __builtin_amdgcn_mfma_f32_16x16x32_bf16(qf[ks], kf, z, 0, 0, 0);
      }
      s[nt] = z;
    }
#pragma unroll
    for (int nt = 0; nt < 4; ++nt)
#pragma unroll
      for (int r = 0; r < 4; ++r) s[nt][r] *= 0.125f;

    // online softmax (quad-group of 16 lanes owns rows quad*4+r)
#pragma unroll
    for (int r = 0; r < 4; ++r){
      float mx = fmaxf(fmaxf(s[0][r], s[1][r]), fmaxf(s[2][r], s[3][r]));
#pragma unroll
      for (int off = 1; off < 16; off <<= 1) mx = fmaxf(mx, __shfl_xor(mx, off));
      float mn = fmaxf(mi[r], mx);
      float al = safe_exp(mi[r] - mn);
      mi[r] = mn;
      float rs = 0.f;
#pragma unroll
      for (int nt = 0; nt < 4; ++nt){
        float pv = safe_exp(s[nt][r] - mn);
        s[nt][r] = pv;
        rs += pv;
      }
#pragma unroll
      for (int off = 1; off < 16; off <<= 1) rs += __shfl_xor(rs, off);
      li[r] = li[r]*al + rs;
#pragma unroll
      for (int dt = 0; dt < 4; ++dt) o[dt][r] *= al;
    }
    // P (C/D layout) -> LDS
#pragma unroll
    for (int nt = 0; nt < 4; ++nt)
#pragma unroll
      for (int r = 0; r < 4; ++r)
        pl[(w*16 + quad*4 + r)*72 + nt*16 + l16] = f2bf(s[nt][r]);

    __syncthreads();   // order the P exchange

    // O += P @ V
#pragma unroll
    for (int ks = 0; ks < 2; ++ks){
      bf16x8 pf = *(const bf16x8*)&pl[(w*16 + l16)*72 + ks*32 + quad*8];
#pragma unroll
      for (int dt = 0; dt < 4; ++dt){
        bf16x8 vf = *(const bf16x8*)&vt[(dt*16 + l16)*72 + ks*32 + quad*8];
        o[dt] = __builtin_amdgcn_mfma_f32_16x16x32_bf16(pf, vf, o[dt], 0, 0, 0);
      }
    }
    __syncthreads();
  }
#pragma unroll
  for (int r = 0; r < 4; ++r){
    float inv = 1.f / li[r];
    const long row = (long)b*4096 + q0 + w*16 + quad*4 + r;
#pragma unroll
    for (int dt = 0; dt < 4; ++dt)
      aop[row*384 + h*64 + dt*16 + l16] = f2bf(o[dt][r] * inv);
  }
}

// ---------------- KNN top-8, fp32 compact coords ----------------
__global__ __launch_bounds__(256) void knn_topk(
    const float* __restrict__ crd, int* __restrict__ idxout)
{
  const int w = threadIdx.x >> 6, lane = threadIdx.x & 63;
  const int row = blockIdx.x * 4 + w;
  const int b = row >> 12, n = row & 4095;
  const long pb = (long)b * 12288;
  const float xn = crd[pb + n], yn = crd[pb + 4096 + n], zn = crd[pb + 8192 + n];
  const float sqn = __fadd_rn(__fadd_rn(__fmul_rn(xn,xn), __fmul_rn(yn,yn)), __fmul_rn(zn,zn));

  float bd[8]; int bi[8];
#pragma unroll
  for (int j = 0; j < 8; ++j){ bd[j] = 3.4e38f; bi[j] = 0x7fffffff; }

  for (int m0 = 0; m0 < 4096; m0 += 64){
    const int m = m0 + lane;
    float xm = crd[pb + m], ym = crd[pb + 4096 + m], zm = crd[pb + 8192 + m];
    float sqm = __fadd_rn(__fadd_rn(__fmul_rn(xm,xm), __fmul_rn(ym,ym)), __fmul_rn(zm,zm));
    float dot = __fadd_rn(__fadd_rn(__fmul_rn(xn,xm), __fmul_rn(yn,ym)), __fmul_rn(zn,zm));
    float v = __fadd_rn(__fadd_rn(sqn, sqm), __fmul_rn(-2.f, dot));
    int vi = m;
#pragma unroll
    for (int j = 0; j < 8; ++j){
      bool c = (v < bd[j]) || (v == bd[j] && vi < bi[j]);
      float td = bd[j]; int ti = bi[j];
      bd[j] = c ? v : td;  bi[j] = c ? vi : ti;
      v = c ? td : v;      vi = c ? ti : vi;
    }
  }
  for (int t = 0; t < 8; ++t){
    float rd = bd[0]; int ri = bi[0]; int rl = lane;
#pragma unroll
    for (int off = 1; off < 64; off <<= 1){
      float od = __shfl_xor(rd, off); int oi = __shfl_xor(ri, off); int ol = __shfl_xor(rl, off);
      bool take = (od < rd) || (od == rd && oi < ri);
      rd = take ? od : rd; ri = take ? oi : ri; rl = take ? ol : rl;
    }
    if (lane == 0) idxout[row*8 + t] = ri;
    if (lane == rl){
#pragma unroll
      for (int j = 0; j < 7; ++j){ bd[j] = bd[j+1]; bi[j] = bi[j+1]; }
      bd[7] = 3.4e38f; bi[7] = 0x7fffffff;
    }
  }
}

// ---------------- gather-max (bf16 in, bf16 out) -> cat1 cols 384..767 ----------------
__global__ __launch_bounds__(384) void knn_gather_max(
    const u16* __restrict__ A1, const u16* __restrict__ A2,
    const int* __restrict__ idx, u16* __restrict__ cat1)
{
  const int row = blockIdx.x;
  const int d = threadIdx.x;
  const int b = row >> 12;
  const float bs = bf2f(A2[(long)row*384 + d]) - bf2f(A1[(long)row*384 + d]);
  float mx = -3.4e38f;
#pragma unroll
  for (int k = 0; k < 8; ++k){
    int r = idx[row*8 + k] & 4095;
    float v = bf2f(A1[(long)(b*4096 + r)*384 + d]) + bs;
    v = (v > 0.f) ? v : 0.2f*v;
    mx = fmaxf(mx, v);
  }
  cat1[(long)row*768 + 384 + d] = f2bf(mx);
}

// ---------------- coords passthrough: compact fp32 -> out fp32 ----------------
__global__ void copy_coords(const float* __restrict__ crd, float* __restrict__ out)
{
  int t = blockIdx.x*256 + threadIdx.x;   // 24576
  int b = t / 12288, r = t % 12288;
  out[(long)b*PTS_STRIDE + r] = crd[t];
}

// ---------------- transpose fin fp32 (B,N,384) -> out fp32 channels 3..386 ----------
__global__ __launch_bounds__(256) void write_out(
    const float* __restrict__ fin, float* __restrict__ out)
{
  __shared__ float tile[64][65];
  const int n0 = blockIdx.x*64, d0 = blockIdx.y*64, b = blockIdx.z;
  const int t = threadIdx.x;
  {
    int nn = t >> 2, dc = (t & 3) * 16;
    const float* src = &fin[((long)(b*4096 + n0 + nn))*384 + d0 + dc];
#pragma unroll
    for (int j = 0; j < 16; ++j) tile[nn][dc + j] = src[j];
  }
  __syncthreads();
  {
    int dd = t >> 2, nc = (t & 3) * 16;
    float* dst = &out[(long)b*PTS_STRIDE + (long)(3+d0+dd)*4096 + n0 + nc];
#pragma unroll
    for (int j = 0; j < 16; ++j) dst[j] = tile[nc + j][dd];
  }
}

extern "C" void kernel_launch(void* const* d_in, const int* in_sizes, int n_in,
                              void* d_out, int out_size, void* d_ws, size_t ws_size,
                              hipStream_t stream) {
  (void)in_sizes; (void)n_in; (void)out_size; (void)ws_size; (void)d_ws;
  float* out = (float*)d_out;          // output dtype = float32 (verified R9)
  char* ws = g_scratch;

  u16*   cv   = (u16*)(ws + OFF_CONV);
  float* crd  = (float*)(ws + OFF_CRDF);
  u16*   wT   = (u16*)(ws + OFF_WT);
  u16*   nf   = (u16*)(ws + OFF_NF);
  u16*   qkv  = (u16*)(ws + OFF_QKV);
  u16*   aop  = (u16*)(ws + OFF_AOP);
  u16*   cat1 = (u16*)(ws + OFF_CAT1);
  u16*   A1b  = (u16*)(ws + OFF_A1);
  u16*   A2b  = (u16*)(ws + OFF_A2);
  u16*   out1 = (u16*)(ws + OFF_OUT1);
  u16*   out2 = (u16*)(ws + OFF_OUT2);
  u16*   h1   = (u16*)(ws + OFF_H1);
  float* fin  = (float*)(ws + OFF_FIN);
  int*   idxb = (int*)(ws + OFF_IDX);

  const u16 *c_points = cv+CV_POINTS, *c_ln1g = cv+CV_LN1G, *c_ln1b = cv+CV_LN1B,
            *c_qkvw = cv+CV_QKVW, *c_aow = cv+CV_AOW, *c_aob = cv+CV_AOB,
            *c_knnw = cv+CV_KNNW, *c_knnb = cv+CV_KNNB, *c_mrgw = cv+CV_MRGW,
            *c_mrgb = cv+CV_MRGB, *c_ln2g = cv+CV_LN2G, *c_ln2b = cv+CV_LN2B,
            *c_ff1w = cv+CV_FF1W, *c_ff1b = cv+CV_FF1B, *c_ff2w = cv+CV_FF2W,
            *c_ff2b = cv+CV_FF2B;
  u16 *wTq = wT+WT_QKV, *wTao = wT+WT_AO, *wTknn = wT+WT_KNN,
      *wTmrg = wT+WT_MRG, *wTff1 = wT+WT_FF1, *wTff2 = wT+WT_FF2;

  // 0. convert inputs -> bf16 (+ fp32 coords); transpose weights for bt=1 staging
  InPtrs ip; for (int i = 0; i < 16; ++i) ip.p[i] = d_in[i];
  convert_inputs<<<1024, 256, 0, stream>>>(cv, crd, ip);
  transpose_k<<<256, 256, 0, stream>>>(c_qkvw, wTq, 384, 1152);
  transpose_k<<<256, 256, 0, stream>>>(c_aow,  wTao, 384, 384);
  transpose_k<<<256, 256, 0, stream>>>(c_knnw, wTknn, 768, 384);
  transpose_k<<<256, 256, 0, stream>>>(c_mrgw, wTmrg, 768, 384);
  transpose_k<<<256, 256, 0, stream>>>(c_ff1w, wTff1, 384, 768);
  transpose_k<<<256, 256, 0, stream>>>(c_ff2w, wTff2, 768, 384);

  // 1. LN1 -> nf
  ln_kernel<<<2048, 256, 0, stream>>>(c_points, c_ln1g, c_ln1b, nf, 0);
  // 2. qkv = nf @ qkv_w
  gemm_k<<<dim3(18,128), 256, 0, stream>>>(nf, 384, wTq, 384, 1,
      qkv, 1152, 0, nullptr, nullptr, 0, 384, 0);
  // 3. flash attention -> aop
  flash_attn<<<dim3(64,6,2), 256, 0, stream>>>(qkv, aop);
  // 4. attn = aop @ attn_out_w + b -> cat1 cols 0..383
  gemm_k<<<dim3(6,128), 256, 0, stream>>>(aop, 384, wTao, 384, 1,
      cat1, 768, 0, c_aob, nullptr, 0, 384, 0);
  // 5. top-8 neighbors (fp32 coords)
  knn_topk<<<2048, 256, 0, stream>>>(crd, idxb);
  // 6. A1 = nf@W1 ; A2 = nf@W2 + knn_b
  gemm_k<<<dim3(6,128), 256, 0, stream>>>(nf, 384, wTknn, 768, 1,
      A1b, 384, 0, nullptr, nullptr, 0, 384, 0);
  gemm_k<<<dim3(6,128), 256, 0, stream>>>(nf, 384, wTknn+384, 768, 1,
      A2b, 384, 0, c_knnb, nullptr, 0, 384, 0);
  // 7. geom -> cat1 cols 384..767
  knn_gather_max<<<8192, 384, 0, stream>>>(A1b, A2b, idxb, cat1);
  // 8. out1 = cat1 @ merge_w + merge_b + attn(resid = cat1 cols 0..383)
  gemm_k<<<dim3(6,128), 256, 0, stream>>>(cat1, 768, wTmrg, 768, 1,
      out1, 384, 0, c_mrgb, cat1, 768, 768, 0);
  // 9. LN2
  ln_kernel<<<2048, 256, 0, stream>>>(out1, c_ln2g, c_ln2b, out2, 1);
  // 10. h1 = gelu(out2 @ ff1_w + ff1_b)
  gemm_k<<<dim3(12,128), 256, 0, stream>>>(out2, 384, wTff1, 384, 1,
      h1, 768, 0, c_ff1b, nullptr, 0, 384, 1);
  // 11. fin = h1 @ ff2_w + ff2_b + out2   (fp32 output)
  gemm_k<<<dim3(6,128), 256, 0, stream>>>(h1, 768, wTff2, 768, 1,
      fin, 384, 1, c_ff2b, out2, 384, 768, 0);
  // 12. assemble fp32 output
  copy_coords<<<96, 256, 0, stream>>>(crd, out);
  write_out<<<dim3(64,6,2), 256, 0, stream>>>(fin, out);
}